// Round 10
// baseline (134.270 us; speedup 1.0000x reference)
//
#include <hip/hip_runtime.h>

constexpr int Bn = 8, Tn = 4096, Dn = 512, Hn = 512;
constexpr int Mn = Bn * Tn;            // 32768 rows
constexpr int CH = 64, NC = Tn / CH;   // 64 chunks of 64 steps

typedef __attribute__((ext_vector_type(8))) short s8v;       // 8 bf16
typedef __attribute__((ext_vector_type(4))) float f4v;       // MFMA acc
typedef __attribute__((ext_vector_type(8))) _Float16 h8v;    // 16B granule: a[0..3], b[0..3]
typedef unsigned short ushort_t;

typedef __attribute__((address_space(1))) const void gv_t;   // global src for load_lds
typedef __attribute__((address_space(3))) void lv_t;         // LDS dst for load_lds

__device__ __forceinline__ short f2bf(float f) {
  unsigned u = __float_as_uint(f);
  u = (u + 0x7fffu + ((u >> 16) & 1u)) >> 16;   // RNE
  return (short)u;
}

// W fp32 [h][512] -> bf16 tiles of 128 rows x 32 k in MFMA-fragment order.
// Tile lb = rt*16 + kt; chunk c = (r>>4)*64 + k8*16 + (r&15), 16B each.
// Blocks [0,64) = Wz, [64,128) = Wh.
__global__ __launch_bounds__(256) void convert_w(
    const float* __restrict__ Wz, const float* __restrict__ Wh,
    ushort_t* __restrict__ Wzb, ushort_t* __restrict__ Whb) {
  int bx = blockIdx.x, tid = threadIdx.x;
  const float* src;
  ushort_t* dst;
  int lb;
  if (bx < 64) { src = Wz; dst = Wzb; lb = bx; }
  else         { src = Wh; dst = Whb; lb = bx - 64; }
  const float* tsrc = src + ((size_t)(lb >> 4) * 128) * Dn + (lb & 15) * 32;
#pragma unroll
  for (int p = 0; p < 2; p++) {
    int idx = tid + p * 256;
    int r = idx >> 2, k8 = idx & 3;
    const float4* sv = reinterpret_cast<const float4*>(tsrc + (size_t)r * Dn + k8 * 8);
    float4 f0 = sv[0], f1 = sv[1];
    s8v v;
    v[0] = f2bf(f0.x); v[1] = f2bf(f0.y); v[2] = f2bf(f0.z); v[3] = f2bf(f0.w);
    v[4] = f2bf(f1.x); v[5] = f2bf(f1.y); v[6] = f2bf(f1.z); v[7] = f2bf(f1.w);
    int c = (r >> 4) * 64 + k8 * 16 + (r & 15);
    *reinterpret_cast<s8v*>(&dst[((size_t)lb * 512 + c) * 8]) = v;
  }
}

// W-stationary barrier-free dual GEMM reading X fp32 DIRECTLY (in-register
// fp32->bf16 cvt; no Xb materialization, no X LDS). Block = (mtp, p): stages
// panel p's FULL W_z,W_h (K=512, 128KB LDS) once, then processes TWO 512-row
// M-tiles (grid = 256 = 1 block/CU, single generation). 8 waves; wave = one
// 64-row chunk x 64 cols per m2. K-loop: X fp32 2xfloat4/frag prefetched one
// step ahead, cvt_pk -> af; W broadcast ds_read; 32 MFMA; zero barriers.
__global__ __launch_bounds__(512, 2) void gemm_act(
    const float* __restrict__ X, const ushort_t* __restrict__ Wzb,
    const ushort_t* __restrict__ Whb,
    const float* __restrict__ bzp, const float* __restrict__ bhp,
    h8v* __restrict__ cab, float* __restrict__ cA, float* __restrict__ cB) {
  __shared__ __align__(16) ushort_t lds[32 * 2048];   // 32 regions x 4KB = 128KB

  int tid = threadIdx.x, lane = tid & 63, wid = tid >> 6;
  int o = blockIdx.x;
  int p = o & 7;                                // 64-col H-panel; same-mtp blocks spread over XCDs, X via L3
  int mtp = o >> 3;                             // [0,32) pair of 512-row M-tiles

  // ---- stage W panel once: region r = m*16+kt (m: 0=Wz,1=Wh), 4KB each ----
#pragma unroll
  for (int q = 0; q < 16; q++) {
    int r = q * 2 + (wid >> 2);                 // wave-uniform region id
    int kt = r & 15;
    const ushort_t* wsrc = (r >= 16 ? Whb : Wzb);
    const ushort_t* s = wsrc + ((size_t)((p >> 1) * 16 + kt)) * 4096 + (p & 1) * 2048 + (tid & 255) * 8;
    __builtin_amdgcn_global_load_lds((gv_t*)s, (lv_t*)(lds + r * 2048 + (tid & 255) * 8), 16, 0, 0);
  }
  __syncthreads();                              // W resident; read-only hereafter

  auto ldW = [&](int kt, s8v* bzf, s8v* bhf) {
#pragma unroll
    for (int j = 0; j < 4; j++) {
      bzf[j] = *reinterpret_cast<const s8v*>(lds + (size_t)kt * 2048 + (j * 64 + lane) * 8);
      bhf[j] = *reinterpret_cast<const s8v*>(lds + (size_t)(16 + kt) * 2048 + (j * 64 + lane) * 8);
    }
  };
  auto cvtFrag = [&](const float4& a, const float4& b) -> s8v {
    union { unsigned u[4]; s8v v; } r;
    asm("v_cvt_pk_bf16_f32 %0, %1, %2" : "=v"(r.u[0]) : "v"(a.x), "v"(a.y));
    asm("v_cvt_pk_bf16_f32 %0, %1, %2" : "=v"(r.u[1]) : "v"(a.z), "v"(a.w));
    asm("v_cvt_pk_bf16_f32 %0, %1, %2" : "=v"(r.u[2]) : "v"(b.x), "v"(b.y));
    asm("v_cvt_pk_bf16_f32 %0, %1, %2" : "=v"(r.u[3]) : "v"(b.z), "v"(b.w));
    return r.v;
  };

  for (int m2 = 0; m2 < 2; m2++) {
    int mt = mtp * 2 + m2;
    int rw = mt * 8 + wid;                      // global chunk id R [0,512)
    // lane's X row/col for fragment i: row = rw*64 + i*16 + (lane&15), k-off (lane>>4)*8
    const float* Xp = X + (size_t)(rw * 64 + (lane & 15)) * Dn + (lane >> 4) * 8;

    auto loadX = [&](int kt, float4* xf) {
#pragma unroll
      for (int i = 0; i < 4; i++) {
        const float4* si = reinterpret_cast<const float4*>(Xp + (size_t)i * 16 * Dn + kt * 32);
        xf[2 * i] = si[0];
        xf[2 * i + 1] = si[1];
      }
    };

    f4v accz[4][4], acch[4][4];
#pragma unroll
    for (int i = 0; i < 4; i++)
#pragma unroll
      for (int j = 0; j < 4; j++) {
        accz[i][j] = (f4v){0.f, 0.f, 0.f, 0.f};
        acch[i][j] = (f4v){0.f, 0.f, 0.f, 0.f};
      }

    float4 xf[8];
    loadX(0, xf);
#pragma unroll
    for (int kt = 0; kt < 16; kt++) {
      s8v af[4];
#pragma unroll
      for (int i = 0; i < 4; i++) af[i] = cvtFrag(xf[2 * i], xf[2 * i + 1]);
      if (kt < 15) loadX(kt + 1, xf);           // 1-step-ahead prefetch
      s8v bzf[4], bhf[4];
      ldW(kt, bzf, bhf);
      __builtin_amdgcn_s_setprio(1);
#pragma unroll
      for (int i = 0; i < 4; i++)
#pragma unroll
        for (int j = 0; j < 4; j++) {
          accz[i][j] = __builtin_amdgcn_mfma_f32_16x16x32_bf16(af[i], bzf[j], accz[i][j], 0, 0, 0);
          acch[i][j] = __builtin_amdgcn_mfma_f32_16x16x32_bf16(af[i], bhf[j], acch[i][j], 0, 0, 0);
        }
      __builtin_amdgcn_s_setprio(0);
    }

    // ---- epilogue: C/D layout col=lane&15, row=(lane>>4)*4+q  [m89/m91] ----
    int R = rw, Cc = p;
    size_t base = (size_t)(R * 8 + Cc) * 1024;
    float bzv[4], bhv[4];
#pragma unroll
    for (int j = 0; j < 4; j++) {
      int h = p * 64 + j * 16 + (lane & 15);
      bzv[j] = bzp[h];
      bhv[j] = bhp[h];
    }
    float QA[4][4], QB[4][4];  // per-(i,j) 4-t composites from ROUNDED fp16 a,b
#pragma unroll
    for (int i = 0; i < 4; i++)
#pragma unroll
      for (int j = 0; j < 4; j++) {
        h8v g;
        float Pa = 1.f, Pb = 0.f;
#pragma unroll
        for (int q = 0; q < 4; q++) {
          float z = 1.f / (1.f + __expf(-(accz[i][j][q] + bzv[j])));
          float e = __expf(2.f * (acch[i][j][q] + bhv[j]));
          float th = 1.f - 2.f / (e + 1.f);
          g[q] = (_Float16)(1.f - z);        // a_t
          g[4 + q] = (_Float16)(z * th);     // b_t
          float a = (float)g[q], b = (float)g[4 + q];
          Pa = a * Pa;                        // t ascending within lane (q)
          Pb = a * Pb + b;
        }
        cab[base + (size_t)((i * 4 + j) * 64 + lane)] = g;
        QA[i][j] = Pa;
        QB[i][j] = Pb;
      }

    // fused chunk summary: compose over lane-groups g=(lane>>4) then i, per j.
#pragma unroll
    for (int j = 0; j < 4; j++) {
      float A = 1.f, Bv = 0.f;
#pragma unroll
      for (int i = 0; i < 4; i++) {
        float a = QA[i][j], b = QB[i][j];
        float ap = __shfl_xor(a, 16), bp = __shfl_xor(b, 16);
        bool hi = (lane & 16) != 0;
        float af_ = hi ? ap : a, bf_ = hi ? bp : b;   // earlier segment
        float as_ = hi ? a : ap, bs_ = hi ? b : bp;   // later segment
        a = as_ * af_; b = as_ * bf_ + bs_;
        ap = __shfl_xor(a, 32); bp = __shfl_xor(b, 32);
        bool hi2 = (lane & 32) != 0;
        af_ = hi2 ? ap : a; bf_ = hi2 ? bp : b;
        as_ = hi2 ? a : ap; bs_ = hi2 ? b : bp;
        a = as_ * af_; b = as_ * bf_ + bs_;
        Bv = a * Bv + b;
        A = a * A;
      }
      if (lane < 16) {
        int h = p * 64 + j * 16 + lane;
        cA[(size_t)R * Hn + h] = A;
        cB[(size_t)R * Hn + h] = Bv;
      }
    }
  }
}

// S2: serial scan over 64 chunk summaries per (b,h) -> h_start per chunk
__global__ __launch_bounds__(256) void scan_heads(
    const float* __restrict__ cA, const float* __restrict__ cB,
    const float* __restrict__ h0p, float* __restrict__ hst) {
  int gid = blockIdx.x * 256 + threadIdx.x;   // 4096 = B*H
  int b = gid >> 9, h = gid & 511;
  float hr = h0p[(size_t)b * Hn + h];
#pragma unroll 8
  for (int c = 0; c < NC; c++) {
    size_t o = (size_t)(b * NC + c) * Hn + h;
    hst[o] = hr;
    hr = fmaf(cA[o], hr, cB[o]);
  }
}

// S3: replay each chunk from its h_start, write fp32 outputs (B,T,H)
__global__ __launch_bounds__(256) void scan_apply(
    const h8v* __restrict__ cab, const float* __restrict__ hst,
    float* __restrict__ out) {
  int h = blockIdx.y * 256 + threadIdx.x;
  int R = blockIdx.x;
  int hl = h & 63, Cc = h >> 6;
  size_t base = (size_t)(R * 8 + Cc) * 1024 + (size_t)(hl >> 4) * 64 + (hl & 15);
  float hr = hst[(size_t)R * Hn + h];
  size_t ob = (size_t)R * 64 * Hn + h;
#pragma unroll
  for (int i = 0; i < 4; i++)
#pragma unroll
    for (int p = 0; p < 4; p++) {
      h8v g = cab[base + i * 256 + p * 16];
#pragma unroll
      for (int q = 0; q < 4; q++) {
        hr = fmaf((float)g[q], hr, (float)g[4 + q]);
        out[ob + (size_t)(i * 16 + p * 4 + q) * Hn] = hr;
      }
    }
}

extern "C" void kernel_launch(void* const* d_in, const int* in_sizes, int n_in,
                              void* d_out, int out_size, void* d_ws, size_t ws_size,
                              hipStream_t stream) {
  const float* X   = (const float*)d_in[0];
  const float* h0p = (const float*)d_in[1];
  const float* Wz  = (const float*)d_in[2];
  const float* bz  = (const float*)d_in[3];
  const float* Wh  = (const float*)d_in[4];
  const float* bh  = (const float*)d_in[5];
  float* out = (float*)d_out;

  char* ws = (char*)d_ws;
  ushort_t* Wzb = (ushort_t*)ws;                                  // 0.5 MB
  ushort_t* Whb = Wzb + (size_t)Hn * Dn;                          // 0.5 MB
  h8v* cab      = (h8v*)(Whb + (size_t)Hn * Dn);                  // 67.1 MB
  // cab = 2*Mn*Hn halves = Mn*Hn/4 granules of 16B
  float* cA     = (float*)(cab + (size_t)Mn * Hn / 4);            // 1 MB
  float* cB     = cA + (size_t)Bn * NC * Hn;                      // 1 MB
  float* hst    = cB + (size_t)Bn * NC * Hn;                      // 1 MB

  convert_w<<<dim3(128), 256, 0, stream>>>(Wz, Wh, Wzb, Whb);

  gemm_act<<<dim3(256), 512, 0, stream>>>(X, Wzb, Whb, bz, bh, cab, cA, cB);

  scan_heads<<<dim3(Bn * Hn / 256), 256, 0, stream>>>(cA, cB, h0p, hst);
  scan_apply<<<dim3(Mn / 64, Hn / 256), 256, 0, stream>>>(cab, hst, out);
}

// Round 11
// 96.680 us; speedup vs baseline: 1.3888x; 1.3888x over previous
//
#include <hip/hip_runtime.h>

constexpr int Bn = 8, Tn = 4096, Dn = 512, Hn = 512;
constexpr int Mn = Bn * Tn;            // 32768 rows
constexpr int CH = 64, NC = Tn / CH;   // 64 chunks of 64 steps

typedef __attribute__((ext_vector_type(8))) short s8v;       // 8 bf16
typedef __attribute__((ext_vector_type(4))) float f4v;       // MFMA acc
typedef __attribute__((ext_vector_type(8))) _Float16 h8v;    // 16B granule: a[0..3], b[0..3]
typedef unsigned short ushort_t;

typedef __attribute__((address_space(1))) const void gv_t;   // global src for load_lds
typedef __attribute__((address_space(3))) void lv_t;         // LDS dst for load_lds

__device__ __forceinline__ short f2bf(float f) {
  unsigned u = __float_as_uint(f);
  u = (u + 0x7fffu + ((u >> 16) & 1u)) >> 16;   // RNE
  return (short)u;
}

// fp32 [rows][512] -> bf16 tiles of 128 rows x 32 k in MFMA-fragment order.
// Tile lb = rt*16 + kt; chunk c = (r>>4)*64 + k8*16 + (r&15), 16B each.
__global__ __launch_bounds__(256) void convert_x(
    const float* __restrict__ X, ushort_t* __restrict__ Xb) {
  int lb = blockIdx.x, tid = threadIdx.x;
  const float* tsrc = X + ((size_t)(lb >> 4) * 128) * Dn + (lb & 15) * 32;
#pragma unroll
  for (int p = 0; p < 2; p++) {
    int idx = tid + p * 256;
    int r = idx >> 2, k8 = idx & 3;
    const float4* sv = reinterpret_cast<const float4*>(tsrc + (size_t)r * Dn + k8 * 8);
    float4 f0 = sv[0], f1 = sv[1];
    s8v v;
    v[0] = f2bf(f0.x); v[1] = f2bf(f0.y); v[2] = f2bf(f0.z); v[3] = f2bf(f0.w);
    v[4] = f2bf(f1.x); v[5] = f2bf(f1.y); v[6] = f2bf(f1.z); v[7] = f2bf(f1.w);
    int c = (r >> 4) * 64 + k8 * 16 + (r & 15);
    *reinterpret_cast<s8v*>(&Xb[((size_t)lb * 512 + c) * 8]) = v;
  }
}

// Same for W. Blocks [0,64) = Wz, [64,128) = Wh.
__global__ __launch_bounds__(256) void convert_w(
    const float* __restrict__ Wz, const float* __restrict__ Wh,
    ushort_t* __restrict__ Wzb, ushort_t* __restrict__ Whb) {
  int bx = blockIdx.x, tid = threadIdx.x;
  const float* src;
  ushort_t* dst;
  int lb;
  if (bx < 64) { src = Wz; dst = Wzb; lb = bx; }
  else         { src = Wh; dst = Whb; lb = bx - 64; }
  const float* tsrc = src + ((size_t)(lb >> 4) * 128) * Dn + (lb & 15) * 32;
#pragma unroll
  for (int p = 0; p < 2; p++) {
    int idx = tid + p * 256;
    int r = idx >> 2, k8 = idx & 3;
    const float4* sv = reinterpret_cast<const float4*>(tsrc + (size_t)r * Dn + k8 * 8);
    float4 f0 = sv[0], f1 = sv[1];
    s8v v;
    v[0] = f2bf(f0.x); v[1] = f2bf(f0.y); v[2] = f2bf(f0.z); v[3] = f2bf(f0.w);
    v[4] = f2bf(f1.x); v[5] = f2bf(f1.y); v[6] = f2bf(f1.z); v[7] = f2bf(f1.w);
    int c = (r >> 4) * 64 + k8 * 16 + (r & 15);
    *reinterpret_cast<s8v*>(&dst[((size_t)lb * 512 + c) * 8]) = v;
  }
}

// W-stationary barrier-free dual GEMM + activations + chunk summaries.
// Block = (mt, p): 512 M-rows x 64 H-cols. Stages panel p's FULL W_z,W_h
// (K=512) into 128KB LDS once (1 barrier total). K-loop: X fragments from
// pre-swizzled Xb via a 4-deep register prefetch queue (~3 steps / ~465cy
// ahead); W streamed one step at a time (32 live regs) via broadcast
// ds_read; 32 MFMA/step; zero barriers. 8 waves; wave = one chunk x 64 cols.
__global__ __launch_bounds__(512, 2) void gemm_act(
    const ushort_t* __restrict__ Xb, const ushort_t* __restrict__ Wzb,
    const ushort_t* __restrict__ Whb,
    const float* __restrict__ bzp, const float* __restrict__ bhp,
    h8v* __restrict__ cab, float* __restrict__ cA, float* __restrict__ cB) {
  __shared__ __align__(16) ushort_t lds[32 * 2048];   // 32 regions x 4KB = 128KB

  int tid = threadIdx.x, lane = tid & 63, wid = tid >> 6;

  // XCD-affinity: XCD x owns mt in [8x, 8x+8); 8 panels of one mt adjacent.
  int o = blockIdx.x;
  int loc = o >> 3;
  int mt = (o & 7) * 8 + (loc >> 3);            // [0,64)  M-tile of 512 rows
  int p = loc & 7;                              // [0,8)   64-col H-panel

  // ---- stage W panel: region r = m*16+kt (m: 0=Wz,1=Wh), 4KB each ----
#pragma unroll
  for (int q = 0; q < 16; q++) {
    int r = q * 2 + (wid >> 2);                 // wave-uniform region id
    int kt = r & 15;
    const ushort_t* wsrc = (r >= 16 ? Whb : Wzb);
    const ushort_t* s = wsrc + ((size_t)((p >> 1) * 16 + kt)) * 4096 + (p & 1) * 2048 + (tid & 255) * 8;
    __builtin_amdgcn_global_load_lds((gv_t*)s, (lv_t*)(lds + r * 2048 + (tid & 255) * 8), 16, 0, 0);
  }

  f4v accz[4][4], acch[4][4];
#pragma unroll
  for (int i = 0; i < 4; i++)
#pragma unroll
    for (int j = 0; j < 4; j++) {
      accz[i][j] = (f4v){0.f, 0.f, 0.f, 0.f};
      acch[i][j] = (f4v){0.f, 0.f, 0.f, 0.f};
    }

  int rw = mt * 8 + wid;                        // global chunk id R [0,512)
  int rt = rw >> 1, half = rw & 1;              // Xb 128-row tile, half select
  const s8v* xs = reinterpret_cast<const s8v*>(Xb) + (size_t)rt * 16 * 512 + (half * 4) * 64 + lane;

  __syncthreads();                              // W resident; read-only hereafter

  auto ldX = [&](s8v* A, int kt) {
#pragma unroll
    for (int i = 0; i < 4; i++) A[i] = xs[kt * 512 + i * 64];
  };
  auto ldW = [&](int kt, s8v* bzf, s8v* bhf) {
#pragma unroll
    for (int j = 0; j < 4; j++) {
      bzf[j] = *reinterpret_cast<const s8v*>(lds + (size_t)kt * 2048 + (j * 64 + lane) * 8);
      bhf[j] = *reinterpret_cast<const s8v*>(lds + (size_t)(16 + kt) * 2048 + (j * 64 + lane) * 8);
    }
  };
  auto mfmaStep = [&](s8v* af, s8v* bzf, s8v* bhf) {
    __builtin_amdgcn_s_setprio(1);
#pragma unroll
    for (int i = 0; i < 4; i++)
#pragma unroll
      for (int j = 0; j < 4; j++) {
        accz[i][j] = __builtin_amdgcn_mfma_f32_16x16x32_bf16(af[i], bzf[j], accz[i][j], 0, 0, 0);
        acch[i][j] = __builtin_amdgcn_mfma_f32_16x16x32_bf16(af[i], bhf[j], acch[i][j], 0, 0, 0);
      }
    __builtin_amdgcn_s_setprio(0);
  };

  // 4-deep X prefetch queue, static rotation (full unroll, rule #20)
  s8v A0[4], A1[4], A2[4], A3[4];
  ldX(A0, 0); ldX(A1, 1); ldX(A2, 2); ldX(A3, 3);

#pragma unroll
  for (int kp = 0; kp < 4; kp++) {
    {
      s8v bz[4], bh[4];
      ldW(4 * kp + 0, bz, bh);
      mfmaStep(A0, bz, bh);
      if (kp < 3) ldX(A0, 4 * kp + 4);
    }
    {
      s8v bz[4], bh[4];
      ldW(4 * kp + 1, bz, bh);
      mfmaStep(A1, bz, bh);
      if (kp < 3) ldX(A1, 4 * kp + 5);
    }
    {
      s8v bz[4], bh[4];
      ldW(4 * kp + 2, bz, bh);
      mfmaStep(A2, bz, bh);
      if (kp < 3) ldX(A2, 4 * kp + 6);
    }
    {
      s8v bz[4], bh[4];
      ldW(4 * kp + 3, bz, bh);
      mfmaStep(A3, bz, bh);
      if (kp < 3) ldX(A3, 4 * kp + 7);
    }
  }

  // ---- epilogue: C/D layout col=lane&15, row=(lane>>4)*4+q  [m89/m91] ----
  int R = rw, Cc = p;
  size_t base = (size_t)(R * 8 + Cc) * 1024;
  float bzv[4], bhv[4];
#pragma unroll
  for (int j = 0; j < 4; j++) {
    int h = p * 64 + j * 16 + (lane & 15);
    bzv[j] = bzp[h];
    bhv[j] = bhp[h];
  }
  float QA[4][4], QB[4][4];   // per-(i,j) 4-t composites from ROUNDED fp16 a,b
#pragma unroll
  for (int i = 0; i < 4; i++)
#pragma unroll
    for (int j = 0; j < 4; j++) {
      h8v g;
      float Pa = 1.f, Pb = 0.f;
#pragma unroll
      for (int q = 0; q < 4; q++) {
        float z = 1.f / (1.f + __expf(-(accz[i][j][q] + bzv[j])));
        float e = __expf(2.f * (acch[i][j][q] + bhv[j]));
        float th = 1.f - 2.f / (e + 1.f);
        g[q] = (_Float16)(1.f - z);        // a_t
        g[4 + q] = (_Float16)(z * th);     // b_t
        float a = (float)g[q], b = (float)g[4 + q];
        Pa = a * Pa;                        // t ascending within lane (q)
        Pb = a * Pb + b;
      }
      cab[base + (size_t)((i * 4 + j) * 64 + lane)] = g;
      QA[i][j] = Pa;
      QB[i][j] = Pb;
    }

  // fused chunk summary: compose over lane-groups g=(lane>>4) then i, per j.
#pragma unroll
  for (int j = 0; j < 4; j++) {
    float A = 1.f, Bv = 0.f;
#pragma unroll
    for (int i = 0; i < 4; i++) {
      float a = QA[i][j], b = QB[i][j];
      float ap = __shfl_xor(a, 16), bp = __shfl_xor(b, 16);
      bool hi = (lane & 16) != 0;
      float af_ = hi ? ap : a, bf_ = hi ? bp : b;   // earlier segment
      float as_ = hi ? a : ap, bs_ = hi ? b : bp;   // later segment
      a = as_ * af_; b = as_ * bf_ + bs_;
      ap = __shfl_xor(a, 32); bp = __shfl_xor(b, 32);
      bool hi2 = (lane & 32) != 0;
      af_ = hi2 ? ap : a; bf_ = hi2 ? bp : b;
      as_ = hi2 ? a : ap; bs_ = hi2 ? b : bp;
      a = as_ * af_; b = as_ * bf_ + bs_;
      Bv = a * Bv + b;
      A = a * A;
    }
    if (lane < 16) {
      int h = p * 64 + j * 16 + lane;
      cA[(size_t)R * Hn + h] = A;
      cB[(size_t)R * Hn + h] = Bv;
    }
  }
}

// S2: serial scan over 64 chunk summaries per (b,h) -> h_start per chunk
__global__ __launch_bounds__(256) void scan_heads(
    const float* __restrict__ cA, const float* __restrict__ cB,
    const float* __restrict__ h0p, float* __restrict__ hst) {
  int gid = blockIdx.x * 256 + threadIdx.x;   // 4096 = B*H
  int b = gid >> 9, h = gid & 511;
  float hr = h0p[(size_t)b * Hn + h];
#pragma unroll 8
  for (int c = 0; c < NC; c++) {
    size_t o = (size_t)(b * NC + c) * Hn + h;
    hst[o] = hr;
    hr = fmaf(cA[o], hr, cB[o]);
  }
}

// S3: replay each chunk from its h_start, write fp32 outputs (B,T,H)
__global__ __launch_bounds__(256) void scan_apply(
    const h8v* __restrict__ cab, const float* __restrict__ hst,
    float* __restrict__ out) {
  int h = blockIdx.y * 256 + threadIdx.x;
  int R = blockIdx.x;
  int hl = h & 63, Cc = h >> 6;
  size_t base = (size_t)(R * 8 + Cc) * 1024 + (size_t)(hl >> 4) * 64 + (hl & 15);
  float hr = hst[(size_t)R * Hn + h];
  size_t ob = (size_t)R * 64 * Hn + h;
#pragma unroll
  for (int i = 0; i < 4; i++)
#pragma unroll
    for (int p = 0; p < 4; p++) {
      h8v g = cab[base + i * 256 + p * 16];
#pragma unroll
      for (int q = 0; q < 4; q++) {
        hr = fmaf((float)g[q], hr, (float)g[4 + q]);
        out[ob + (size_t)(i * 16 + p * 4 + q) * Hn] = hr;
      }
    }
}

extern "C" void kernel_launch(void* const* d_in, const int* in_sizes, int n_in,
                              void* d_out, int out_size, void* d_ws, size_t ws_size,
                              hipStream_t stream) {
  const float* X   = (const float*)d_in[0];
  const float* h0p = (const float*)d_in[1];
  const float* Wz  = (const float*)d_in[2];
  const float* bz  = (const float*)d_in[3];
  const float* Wh  = (const float*)d_in[4];
  const float* bh  = (const float*)d_in[5];
  float* out = (float*)d_out;

  char* ws = (char*)d_ws;
  ushort_t* Xb  = (ushort_t*)ws;                                  // 33.6 MB
  ushort_t* Wzb = Xb + (size_t)Mn * Dn;                           // 0.5 MB
  ushort_t* Whb = Wzb + (size_t)Hn * Dn;                          // 0.5 MB
  h8v* cab      = (h8v*)(Whb + (size_t)Hn * Dn);                  // 67.1 MB
  // cab = 2*Mn*Hn halves = Mn*Hn/4 granules of 16B
  float* cA     = (float*)(cab + (size_t)Mn * Hn / 4);            // 1 MB
  float* cB     = cA + (size_t)Bn * NC * Hn;                      // 1 MB
  float* hst    = cB + (size_t)Bn * NC * Hn;                      // 1 MB

  convert_x<<<dim3(4096), 256, 0, stream>>>(X, Xb);
  convert_w<<<dim3(128), 256, 0, stream>>>(Wz, Wh, Wzb, Whb);

  gemm_act<<<dim3(512), 512, 0, stream>>>(Xb, Wzb, Whb, bz, bh, cab, cA, cB);

  scan_heads<<<dim3(Bn * Hn / 256), 256, 0, stream>>>(cA, cB, h0p, hst);
  scan_apply<<<dim3(Mn / 64, Hn / 256), 256, 0, stream>>>(cab, hst, out);
}

// Round 12
// 96.148 us; speedup vs baseline: 1.3965x; 1.0055x over previous
//
#include <hip/hip_runtime.h>

constexpr int Bn = 8, Tn = 4096, Dn = 512, Hn = 512;
constexpr int Mn = Bn * Tn;            // 32768 rows
constexpr int CH = 64, NC = Tn / CH;   // 64 chunks of 64 steps

typedef __attribute__((ext_vector_type(8))) short s8v;       // 8 bf16
typedef __attribute__((ext_vector_type(4))) float f4v;       // MFMA acc
typedef __attribute__((ext_vector_type(8))) _Float16 h8v;    // 16B granule: a[0..3], b[0..3]
typedef unsigned short ushort_t;

typedef __attribute__((address_space(1))) const void gv_t;   // global src for load_lds
typedef __attribute__((address_space(3))) void lv_t;         // LDS dst for load_lds

__device__ __forceinline__ short f2bf(float f) {
  unsigned u = __float_as_uint(f);
  u = (u + 0x7fffu + ((u >> 16) & 1u)) >> 16;   // RNE
  return (short)u;
}

// fp32 [rows][512] -> bf16 tiles of 128 rows x 32 k in MFMA-fragment order.
// Tile lb = rt*16 + kt; chunk c = (r>>4)*64 + k8*16 + (r&15), 16B each.
__global__ __launch_bounds__(256) void convert_x(
    const float* __restrict__ X, ushort_t* __restrict__ Xb) {
  int lb = blockIdx.x, tid = threadIdx.x;
  const float* tsrc = X + ((size_t)(lb >> 4) * 128) * Dn + (lb & 15) * 32;
#pragma unroll
  for (int p = 0; p < 2; p++) {
    int idx = tid + p * 256;
    int r = idx >> 2, k8 = idx & 3;
    const float4* sv = reinterpret_cast<const float4*>(tsrc + (size_t)r * Dn + k8 * 8);
    float4 f0 = sv[0], f1 = sv[1];
    s8v v;
    v[0] = f2bf(f0.x); v[1] = f2bf(f0.y); v[2] = f2bf(f0.z); v[3] = f2bf(f0.w);
    v[4] = f2bf(f1.x); v[5] = f2bf(f1.y); v[6] = f2bf(f1.z); v[7] = f2bf(f1.w);
    int c = (r >> 4) * 64 + k8 * 16 + (r & 15);
    *reinterpret_cast<s8v*>(&Xb[((size_t)lb * 512 + c) * 8]) = v;
  }
}

// Same for W. Blocks [0,64) = Wz, [64,128) = Wh.
__global__ __launch_bounds__(256) void convert_w(
    const float* __restrict__ Wz, const float* __restrict__ Wh,
    ushort_t* __restrict__ Wzb, ushort_t* __restrict__ Whb) {
  int bx = blockIdx.x, tid = threadIdx.x;
  const float* src;
  ushort_t* dst;
  int lb;
  if (bx < 64) { src = Wz; dst = Wzb; lb = bx; }
  else         { src = Wh; dst = Whb; lb = bx - 64; }
  const float* tsrc = src + ((size_t)(lb >> 4) * 128) * Dn + (lb & 15) * 32;
#pragma unroll
  for (int p = 0; p < 2; p++) {
    int idx = tid + p * 256;
    int r = idx >> 2, k8 = idx & 3;
    const float4* sv = reinterpret_cast<const float4*>(tsrc + (size_t)r * Dn + k8 * 8);
    float4 f0 = sv[0], f1 = sv[1];
    s8v v;
    v[0] = f2bf(f0.x); v[1] = f2bf(f0.y); v[2] = f2bf(f0.z); v[3] = f2bf(f0.w);
    v[4] = f2bf(f1.x); v[5] = f2bf(f1.y); v[6] = f2bf(f1.z); v[7] = f2bf(f1.w);
    int c = (r >> 4) * 64 + k8 * 16 + (r & 15);
    *reinterpret_cast<s8v*>(&dst[((size_t)lb * 512 + c) * 8]) = v;
  }
}

// W-stationary barrier-free dual GEMM + activations + chunk summaries.
// Block = (mt, p): 512 M-rows x 64 H-cols; full W panel (K=512) in 128KB LDS.
// WAVE PHASE-STAGGER: the two waves of each SIMD traverse K with opposite
// phase (kt = n ^ s, s = 8 for wid>=4) so their ds_read-wait and MFMA phases
// interleave instead of lockstep-colliding. fp32 acc order change is benign.
__global__ __launch_bounds__(512, 2) void gemm_act(
    const ushort_t* __restrict__ Xb, const ushort_t* __restrict__ Wzb,
    const ushort_t* __restrict__ Whb,
    const float* __restrict__ bzp, const float* __restrict__ bhp,
    h8v* __restrict__ cab, float* __restrict__ cA, float* __restrict__ cB) {
  __shared__ __align__(16) ushort_t lds[32 * 2048];   // 32 regions x 4KB = 128KB

  int tid = threadIdx.x, lane = tid & 63, wid = tid >> 6;

  // XCD-affinity: XCD x owns mt in [8x, 8x+8); 8 panels of one mt adjacent.
  int o = blockIdx.x;
  int loc = o >> 3;
  int mt = (o & 7) * 8 + (loc >> 3);            // [0,64)  M-tile of 512 rows
  int p = loc & 7;                              // [0,8)   64-col H-panel

  // ---- stage W panel: region r = m*16+kt (m: 0=Wz,1=Wh), 4KB each ----
#pragma unroll
  for (int q = 0; q < 16; q++) {
    int r = q * 2 + (wid >> 2);                 // wave-uniform region id
    int kt = r & 15;
    const ushort_t* wsrc = (r >= 16 ? Whb : Wzb);
    const ushort_t* s = wsrc + ((size_t)((p >> 1) * 16 + kt)) * 4096 + (p & 1) * 2048 + (tid & 255) * 8;
    __builtin_amdgcn_global_load_lds((gv_t*)s, (lv_t*)(lds + r * 2048 + (tid & 255) * 8), 16, 0, 0);
  }

  f4v accz[4][4], acch[4][4];
#pragma unroll
  for (int i = 0; i < 4; i++)
#pragma unroll
    for (int j = 0; j < 4; j++) {
      accz[i][j] = (f4v){0.f, 0.f, 0.f, 0.f};
      acch[i][j] = (f4v){0.f, 0.f, 0.f, 0.f};
    }

  int rw = mt * 8 + wid;                        // global chunk id R [0,512)
  int rt = rw >> 1, half = rw & 1;              // Xb 128-row tile, half select
  const s8v* xs = reinterpret_cast<const s8v*>(Xb) + (size_t)rt * 16 * 512 + (half * 4) * 64 + lane;

  int sph = ((wid >> 2) & 1) * 8;               // K-phase stagger per SIMD-pair

  __syncthreads();                              // W resident; read-only hereafter

  auto ldX = [&](s8v* A, int kt) {
#pragma unroll
    for (int i = 0; i < 4; i++) A[i] = xs[kt * 512 + i * 64];
  };
  auto ldW = [&](int kt, s8v* bzf, s8v* bhf) {
#pragma unroll
    for (int j = 0; j < 4; j++) {
      bzf[j] = *reinterpret_cast<const s8v*>(lds + (size_t)kt * 2048 + (j * 64 + lane) * 8);
      bhf[j] = *reinterpret_cast<const s8v*>(lds + (size_t)(16 + kt) * 2048 + (j * 64 + lane) * 8);
    }
  };
  auto mfmaStep = [&](s8v* af, s8v* bzf, s8v* bhf) {
    __builtin_amdgcn_s_setprio(1);
#pragma unroll
    for (int i = 0; i < 4; i++)
#pragma unroll
      for (int j = 0; j < 4; j++) {
        accz[i][j] = __builtin_amdgcn_mfma_f32_16x16x32_bf16(af[i], bzf[j], accz[i][j], 0, 0, 0);
        acch[i][j] = __builtin_amdgcn_mfma_f32_16x16x32_bf16(af[i], bhf[j], acch[i][j], 0, 0, 0);
      }
    __builtin_amdgcn_s_setprio(0);
  };

  // 4-deep X prefetch queue, static rotation; kt = n ^ sph (wave-uniform phase)
  s8v A0[4], A1[4], A2[4], A3[4];
  ldX(A0, 0 ^ sph); ldX(A1, 1 ^ sph); ldX(A2, 2 ^ sph); ldX(A3, 3 ^ sph);

#pragma unroll
  for (int kp = 0; kp < 4; kp++) {
    {
      s8v bz[4], bh[4];
      ldW((4 * kp + 0) ^ sph, bz, bh);
      mfmaStep(A0, bz, bh);
      if (kp < 3) ldX(A0, (4 * kp + 4) ^ sph);
    }
    {
      s8v bz[4], bh[4];
      ldW((4 * kp + 1) ^ sph, bz, bh);
      mfmaStep(A1, bz, bh);
      if (kp < 3) ldX(A1, (4 * kp + 5) ^ sph);
    }
    {
      s8v bz[4], bh[4];
      ldW((4 * kp + 2) ^ sph, bz, bh);
      mfmaStep(A2, bz, bh);
      if (kp < 3) ldX(A2, (4 * kp + 6) ^ sph);
    }
    {
      s8v bz[4], bh[4];
      ldW((4 * kp + 3) ^ sph, bz, bh);
      mfmaStep(A3, bz, bh);
      if (kp < 3) ldX(A3, (4 * kp + 7) ^ sph);
    }
  }

  // ---- epilogue: C/D layout col=lane&15, row=(lane>>4)*4+q  [m89/m91] ----
  int R = rw, Cc = p;
  size_t base = (size_t)(R * 8 + Cc) * 1024;
  float bzv[4], bhv[4];
#pragma unroll
  for (int j = 0; j < 4; j++) {
    int h = p * 64 + j * 16 + (lane & 15);
    bzv[j] = bzp[h];
    bhv[j] = bhp[h];
  }
  float QA[4][4], QB[4][4];   // per-(i,j) 4-t composites from ROUNDED fp16 a,b
#pragma unroll
  for (int i = 0; i < 4; i++)
#pragma unroll
    for (int j = 0; j < 4; j++) {
      h8v g;
      float Pa = 1.f, Pb = 0.f;
#pragma unroll
      for (int q = 0; q < 4; q++) {
        float z = 1.f / (1.f + __expf(-(accz[i][j][q] + bzv[j])));
        float e = __expf(2.f * (acch[i][j][q] + bhv[j]));
        float th = 1.f - 2.f / (e + 1.f);
        g[q] = (_Float16)(1.f - z);        // a_t
        g[4 + q] = (_Float16)(z * th);     // b_t
        float a = (float)g[q], b = (float)g[4 + q];
        Pa = a * Pa;                        // t ascending within lane (q)
        Pb = a * Pb + b;
      }
      cab[base + (size_t)((i * 4 + j) * 64 + lane)] = g;
      QA[i][j] = Pa;
      QB[i][j] = Pb;
    }

  // fused chunk summary: compose over lane-groups g=(lane>>4) then i, per j.
#pragma unroll
  for (int j = 0; j < 4; j++) {
    float A = 1.f, Bv = 0.f;
#pragma unroll
    for (int i = 0; i < 4; i++) {
      float a = QA[i][j], b = QB[i][j];
      float ap = __shfl_xor(a, 16), bp = __shfl_xor(b, 16);
      bool hi = (lane & 16) != 0;
      float af_ = hi ? ap : a, bf_ = hi ? bp : b;   // earlier segment
      float as_ = hi ? a : ap, bs_ = hi ? b : bp;   // later segment
      a = as_ * af_; b = as_ * bf_ + bs_;
      ap = __shfl_xor(a, 32); bp = __shfl_xor(b, 32);
      bool hi2 = (lane & 32) != 0;
      af_ = hi2 ? ap : a; bf_ = hi2 ? bp : b;
      as_ = hi2 ? a : ap; bs_ = hi2 ? b : bp;
      a = as_ * af_; b = as_ * bf_ + bs_;
      Bv = a * Bv + b;
      A = a * A;
    }
    if (lane < 16) {
      int h = p * 64 + j * 16 + lane;
      cA[(size_t)R * Hn + h] = A;
      cB[(size_t)R * Hn + h] = Bv;
    }
  }
}

// S2: serial scan over 64 chunk summaries per (b,h) -> h_start per chunk
__global__ __launch_bounds__(256) void scan_heads(
    const float* __restrict__ cA, const float* __restrict__ cB,
    const float* __restrict__ h0p, float* __restrict__ hst) {
  int gid = blockIdx.x * 256 + threadIdx.x;   // 4096 = B*H
  int b = gid >> 9, h = gid & 511;
  float hr = h0p[(size_t)b * Hn + h];
#pragma unroll 8
  for (int c = 0; c < NC; c++) {
    size_t o = (size_t)(b * NC + c) * Hn + h;
    hst[o] = hr;
    hr = fmaf(cA[o], hr, cB[o]);
  }
}

// S3: replay each chunk from its h_start, write fp32 outputs (B,T,H)
__global__ __launch_bounds__(256) void scan_apply(
    const h8v* __restrict__ cab, const float* __restrict__ hst,
    float* __restrict__ out) {
  int h = blockIdx.y * 256 + threadIdx.x;
  int R = blockIdx.x;
  int hl = h & 63, Cc = h >> 6;
  size_t base = (size_t)(R * 8 + Cc) * 1024 + (size_t)(hl >> 4) * 64 + (hl & 15);
  float hr = hst[(size_t)R * Hn + h];
  size_t ob = (size_t)R * 64 * Hn + h;
#pragma unroll
  for (int i = 0; i < 4; i++)
#pragma unroll
    for (int p = 0; p < 4; p++) {
      h8v g = cab[base + i * 256 + p * 16];
#pragma unroll
      for (int q = 0; q < 4; q++) {
        hr = fmaf((float)g[q], hr, (float)g[4 + q]);
        out[ob + (size_t)(i * 16 + p * 4 + q) * Hn] = hr;
      }
    }
}

extern "C" void kernel_launch(void* const* d_in, const int* in_sizes, int n_in,
                              void* d_out, int out_size, void* d_ws, size_t ws_size,
                              hipStream_t stream) {
  const float* X   = (const float*)d_in[0];
  const float* h0p = (const float*)d_in[1];
  const float* Wz  = (const float*)d_in[2];
  const float* bz  = (const float*)d_in[3];
  const float* Wh  = (const float*)d_in[4];
  const float* bh  = (const float*)d_in[5];
  float* out = (float*)d_out;

  char* ws = (char*)d_ws;
  ushort_t* Xb  = (ushort_t*)ws;                                  // 33.6 MB
  ushort_t* Wzb = Xb + (size_t)Mn * Dn;                           // 0.5 MB
  ushort_t* Whb = Wzb + (size_t)Hn * Dn;                          // 0.5 MB
  h8v* cab      = (h8v*)(Whb + (size_t)Hn * Dn);                  // 67.1 MB
  // cab = 2*Mn*Hn halves = Mn*Hn/4 granules of 16B
  float* cA     = (float*)(cab + (size_t)Mn * Hn / 4);            // 1 MB
  float* cB     = cA + (size_t)Bn * NC * Hn;                      // 1 MB
  float* hst    = cB + (size_t)Bn * NC * Hn;                      // 1 MB

  convert_x<<<dim3(4096), 256, 0, stream>>>(X, Xb);
  convert_w<<<dim3(128), 256, 0, stream>>>(Wz, Wh, Wzb, Whb);

  gemm_act<<<dim3(512), 512, 0, stream>>>(Xb, Wzb, Whb, bz, bh, cab, cA, cB);

  scan_heads<<<dim3(Bn * Hn / 256), 256, 0, stream>>>(cA, cB, h0p, hst);
  scan_apply<<<dim3(Mn / 64, Hn / 256), 256, 0, stream>>>(cab, hst, out);
}